// Round 3
// baseline (521.006 us; speedup 1.0000x reference)
//
#include <hip/hip_runtime.h>
#include <stdint.h>

typedef unsigned short u16;
typedef unsigned int   u32;
typedef __attribute__((ext_vector_type(2))) float f32x2;
typedef __attribute__((ext_vector_type(4))) float f32x4;
typedef __attribute__((ext_vector_type(8))) short s16x8;

// RNE f32 -> bf16 (used where cheap); staging uses truncation via v_perm
__device__ __forceinline__ u16 f2bf(float f) {
    u32 x = __float_as_uint(f);
    x += 0x7fffu + ((x >> 16) & 1u);
    return (u16)(x >> 16);
}
__device__ __forceinline__ float tanh_fast(float x) {
    return 1.f - 2.f / (__expf(2.f * x) + 1.f);
}
__device__ __forceinline__ float sigm(float x) {
    return 1.f / (1.f + __expf(-x));
}

#define BM 128
#define BN 128
#define BK 64

// load 8 consecutive f32, truncate to bf16, pack to s16x8 (4 u32 via byte-perm)
__device__ __forceinline__ s16x8 cvt8(const float* p) {
    union { s16x8 v; u32 w[4]; } r;
    f32x4 x0 = *(const f32x4*)p;
    f32x4 x1 = *(const f32x4*)(p + 4);
    r.w[0] = __builtin_amdgcn_perm(__float_as_uint(x0[1]), __float_as_uint(x0[0]), 0x07060302u);
    r.w[1] = __builtin_amdgcn_perm(__float_as_uint(x0[3]), __float_as_uint(x0[2]), 0x07060302u);
    r.w[2] = __builtin_amdgcn_perm(__float_as_uint(x1[1]), __float_as_uint(x1[0]), 0x07060302u);
    r.w[3] = __builtin_amdgcn_perm(__float_as_uint(x1[3]), __float_as_uint(x1[2]), 0x07060302u);
    return r.v;
}

// C[r,n] = sum_k A[r,k]*B[n,k]  (K-contiguous operands; fp32 operands converted
// to bf16 in staging when AF32/BF32; bf16 MFMA, fp32 acc)
// B row pointer switches from B1 (ldb1) to B2 (ldb2) at k==ksplitB.
// EPI 0: outF[r*N+n] = acc + bias1[n] + bias2[n]
// EPI 1: t = tanh(acc + hidb[(r/196)*N+n]) * wscore[n]; reduce over n -> atomicAdd(scores[r])
// EPI 2: atomicAdd(outF[r*N+n], acc)   (split-K)
template<int EPI, bool AF32, bool BF32>
__global__ __launch_bounds__(256) void gemm_bt(
    const void* __restrict__ Ag, const void* __restrict__ B1, const void* __restrict__ B2,
    int lda, int ldb1, int ldb2, int ksplitB, int N, int klen,
    float* __restrict__ outF,
    const float* __restrict__ bias1, const float* __restrict__ bias2,
    const float* __restrict__ hidb, const float* __restrict__ wscore,
    float* __restrict__ scores)
{
    __shared__ __align__(16) u16 As[BM * BK];
    __shared__ __align__(16) u16 Bs[BN * BK];
    const int tid = threadIdx.x;
    const int l   = tid & 63;
    const int m0  = blockIdx.y * BM;
    const int n0  = blockIdx.x * BN;
    const int kbeg = blockIdx.z * klen;
    const int kend = kbeg + klen;
    const int w  = tid >> 6;
    const int wr = (w >> 1) * 64;
    const int wc = (w & 1) * 64;
    const int srow = tid >> 3;        // 0..31
    const int skc  = (tid & 7) * 8;   // 0..56

    f32x4 acc[4][4] = {};

    for (int kt = kbeg; kt < kend; kt += BK) {
        s16x8 va[4], vb[4];
        #pragma unroll
        for (int c = 0; c < 4; ++c) {
            int row = c * 32 + srow;
            size_t aoff = (size_t)(m0 + row) * lda + kt + skc;
            if constexpr (AF32) va[c] = cvt8((const float*)Ag + aoff);
            else                va[c] = *(const s16x8*)((const u16*)Ag + aoff);
            int kg = kt + skc;
            if constexpr (BF32) {
                const float* bp = (kg < ksplitB)
                    ? ((const float*)B1 + (size_t)(n0 + row) * ldb1 + kg)
                    : ((const float*)B2 + (size_t)(n0 + row) * ldb2 + (kg - ksplitB));
                vb[c] = cvt8(bp);
            } else {
                const u16* bp = (kg < ksplitB)
                    ? ((const u16*)B1 + (size_t)(n0 + row) * ldb1 + kg)
                    : ((const u16*)B2 + (size_t)(n0 + row) * ldb2 + (kg - ksplitB));
                vb[c] = *(const s16x8*)bp;
            }
        }
        __syncthreads();   // prior iteration's LDS reads complete
        #pragma unroll
        for (int c = 0; c < 4; ++c) {
            int row = c * 32 + srow;
            *(s16x8*)(As + row * BK + skc) = va[c];
            *(s16x8*)(Bs + row * BK + skc) = vb[c];
        }
        __syncthreads();   // tile visible
        #pragma unroll
        for (int kk = 0; kk < BK; kk += 32) {
            s16x8 af[4], bg[4];
            #pragma unroll
            for (int i = 0; i < 4; ++i)
                af[i] = *(const s16x8*)(As + (wr + i * 16 + (l & 15)) * BK + kk + (l >> 4) * 8);
            #pragma unroll
            for (int j = 0; j < 4; ++j)
                bg[j] = *(const s16x8*)(Bs + (wc + j * 16 + (l & 15)) * BK + kk + (l >> 4) * 8);
            #pragma unroll
            for (int i = 0; i < 4; ++i)
                #pragma unroll
                for (int j = 0; j < 4; ++j)
                    acc[i][j] = __builtin_amdgcn_mfma_f32_16x16x32_bf16(af[i], bg[j], acc[i][j], 0, 0, 0);
        }
    }

    // C/D layout (m89-verified): col = lane&15, row = (lane>>4)*4 + reg
    const int col0 = l & 15;
    const int rgrp = l >> 4;

    if (EPI == 0) {
        #pragma unroll
        for (int j = 0; j < 4; ++j) {
            int gcol = n0 + wc + j * 16 + col0;
            float bsum = bias1[gcol] + bias2[gcol];
            #pragma unroll
            for (int i = 0; i < 4; ++i)
                #pragma unroll
                for (int q = 0; q < 4; ++q) {
                    int grow = m0 + wr + i * 16 + rgrp * 4 + q;
                    outF[(size_t)grow * N + gcol] = acc[i][j][q] + bsum;
                }
        }
    } else if (EPI == 1) {
        float wsv[4]; int gcol[4];
        #pragma unroll
        for (int j = 0; j < 4; ++j) {
            gcol[j] = n0 + wc + j * 16 + col0;
            wsv[j] = wscore[gcol[j]];
        }
        #pragma unroll
        for (int i = 0; i < 4; ++i) {
            #pragma unroll
            for (int q = 0; q < 4; ++q) {
                int grow = m0 + wr + i * 16 + rgrp * 4 + q;
                int bb = grow / 196;
                const float* hb = hidb + (size_t)bb * N;
                float s = 0.f;
                #pragma unroll
                for (int j = 0; j < 4; ++j) {
                    float x = acc[i][j][q] + hb[gcol[j]];
                    s += tanh_fast(x) * wsv[j];
                }
                s += __shfl_xor(s, 1);
                s += __shfl_xor(s, 2);
                s += __shfl_xor(s, 4);
                s += __shfl_xor(s, 8);
                if (col0 == 0) atomicAdd(&scores[grow], s);
            }
        }
    } else {
        #pragma unroll
        for (int j = 0; j < 4; ++j) {
            int gcol = n0 + wc + j * 16 + col0;
            #pragma unroll
            for (int i = 0; i < 4; ++i)
                #pragma unroll
                for (int q = 0; q < 4; ++q) {
                    int grow = m0 + wr + i * 16 + rgrp * 4 + q;
                    atomicAdd(&outF[(size_t)grow * N + gcol], acc[i][j][q]);
                }
        }
    }
}

// One block per batch row b: softmax over L=196 scores, att_res = sum_l p_l*att[b,l,:],
// X[b] = [xt | att_res | h_prev] packed bf16 (K=1536) for the gates GEMM.
__global__ __launch_bounds__(256) void softmax_attres(
    const float* __restrict__ att, const float* __restrict__ scores,
    const float* __restrict__ xt, const float* __restrict__ h0,
    u16* __restrict__ X)
{
    const int b = blockIdx.x;
    const int tid = threadIdx.x;
    __shared__ float p[200];
    __shared__ float redm[4], reds[4];

    float s = (tid < 196) ? scores[b * 196 + tid] : -3.0e38f;
    float m = s;
    #pragma unroll
    for (int d = 32; d; d >>= 1) m = fmaxf(m, __shfl_xor(m, d));
    if ((tid & 63) == 0) redm[tid >> 6] = m;
    __syncthreads();
    m = fmaxf(fmaxf(redm[0], redm[1]), fmaxf(redm[2], redm[3]));

    float e = (tid < 196) ? __expf(s - m) : 0.f;
    float sum = e;
    #pragma unroll
    for (int d = 32; d; d >>= 1) sum += __shfl_xor(sum, d);
    if ((tid & 63) == 0) reds[tid >> 6] = sum;
    __syncthreads();
    sum = reds[0] + reds[1] + reds[2] + reds[3];
    if (tid < 196) p[tid] = e / sum;
    __syncthreads();

    // att_res: each thread owns 2 consecutive features
    const f32x2* att2 = (const f32x2*)(att + (size_t)b * 196 * 512);
    float a0 = 0.f, a1 = 0.f;
    for (int lq = 0; lq < 196; ++lq) {
        f32x2 u = att2[(size_t)lq * 256 + tid];
        float pl = p[lq];
        a0 = fmaf(pl, u[0], a0);
        a1 = fmaf(pl, u[1], a1);
    }
    u16* Xr = X + (size_t)b * 1536;
    ((u32*)(Xr + 512))[tid] = ((u32)f2bf(a1) << 16) | (u32)f2bf(a0);
    f32x2 xv = ((const f32x2*)(xt + (size_t)b * 512))[tid];
    ((u32*)Xr)[tid] = ((u32)f2bf(xv[1]) << 16) | (u32)f2bf(xv[0]);
    f32x2 hv = ((const f32x2*)(h0 + (size_t)b * 512))[tid];
    ((u32*)(Xr + 1024))[tid] = ((u32)f2bf(hv[1]) << 16) | (u32)f2bf(hv[0]);
}

// Elementwise LSTM: gate order i,f,g,o. out = [h | h | c] fp32.
__global__ __launch_bounds__(256) void lstm_ep(
    const float* __restrict__ gates, const float* __restrict__ c0, float* __restrict__ out)
{
    int idx = blockIdx.x * 256 + threadIdx.x;     // 0..262143
    int b = idx >> 9, hh = idx & 511;
    const float* g = gates + ((size_t)b << 11);
    float i_ = sigm(g[hh]);
    float f_ = sigm(g[512 + hh]);
    float g_ = tanh_fast(g[1024 + hh]);
    float o_ = sigm(g[1536 + hh]);
    float c = f_ * c0[idx] + i_ * g_;
    float h = o_ * tanh_fast(c);
    out[idx] = h;
    out[262144 + idx] = h;
    out[524288 + idx] = c;
}

extern "C" void kernel_launch(void* const* d_in, const int* in_sizes, int n_in,
                              void* d_out, int out_size, void* d_ws, size_t ws_size,
                              hipStream_t stream) {
    const float* xt   = (const float*)d_in[0];
    // d_in[1] = fc_feats (unused by reference)
    const float* att  = (const float*)d_in[2];
    const float* h0   = (const float*)d_in[3];
    const float* c0   = (const float*)d_in[4];
    const float* Wctx = (const float*)d_in[5];
    const float* bctx = (const float*)d_in[6];
    const float* Whid = (const float*)d_in[7];
    const float* bhid = (const float*)d_in[8];
    const float* wsc  = (const float*)d_in[9];
    // d_in[10] = b_score (cancels under softmax)
    const float* Wih  = (const float*)d_in[11];
    const float* Whh  = (const float*)d_in[12];
    float* out = (float*)d_out;

    char* ws = (char*)d_ws;
    float* hidb   = (float*)(ws);                 // 512*512 f32   = 1,048,576 B
    float* scores = (float*)(ws + 1048576);       // 100352 f32    =   401,408 B
    float* gates  = (float*)(ws + 1449984);       // 512*2048 f32  = 4,194,304 B
    u16*   X      = (u16*)  (ws + 5644288);       // 512*1536 bf16 = 1,572,864 B

    // zero the atomically-accumulated regions (scores + gates)
    hipMemsetAsync(ws + 1048576, 0, 4595712, stream);

    // 1) hidb[b,a] = h_prev @ W_hid^T + b_hid + b_ctx      (M=512,N=512,K=512)
    gemm_bt<0, true, true><<<dim3(4, 4, 1), 256, 0, stream>>>(
        h0, Whid, Whid, 512, 512, 512, 1 << 28, 512, 512,
        hidb, bhid, bctx, nullptr, nullptr, nullptr);

    // 2) scores[b,l] += sum_a tanh(att@Wctx^T + hidb)*w_score  (M=100352,N=512,K=512)
    gemm_bt<1, true, true><<<dim3(4, 784, 1), 256, 0, stream>>>(
        att, Wctx, Wctx, 512, 512, 512, 1 << 28, 512, 512,
        nullptr, nullptr, nullptr, hidb, wsc, scores);

    // 3) softmax + att_res + X = [xt | att_res | h_prev] (bf16)
    softmax_attres<<<512, 256, 0, stream>>>(att, scores, xt, h0, X);

    // 4) gates = X @ [W_ih | W_hh]^T   (M=512,N=2048,K=1536, split-K=4)
    gemm_bt<2, false, true><<<dim3(16, 4, 4), 256, 0, stream>>>(
        X, Wih, Whh, 1536, 1024, 512, 1024, 2048, 384,
        gates, nullptr, nullptr, nullptr, nullptr, nullptr);

    // 5) elementwise LSTM -> out = [h | h | c] fp32
    lstm_ep<<<1024, 256, 0, stream>>>(gates, c0, out);
}

// Round 4
// 511.500 us; speedup vs baseline: 1.0186x; 1.0186x over previous
//
#include <hip/hip_runtime.h>
#include <stdint.h>

typedef unsigned short u16;
typedef unsigned int   u32;
typedef __attribute__((ext_vector_type(2))) float f32x2;
typedef __attribute__((ext_vector_type(4))) float f32x4;
typedef __attribute__((ext_vector_type(8))) short s16x8;

__device__ __forceinline__ u16 f2bf(float f) {
    u32 x = __float_as_uint(f);
    x += 0x7fffu + ((x >> 16) & 1u);
    return (u16)(x >> 16);
}
__device__ __forceinline__ float tanh_fast(float x) {
    return 1.f - 2.f / (__expf(2.f * x) + 1.f);
}
__device__ __forceinline__ float sigm(float x) {
    return 1.f / (1.f + __expf(-x));
}
// pack 8 f32 (two f32x4) -> 8 bf16 by truncation (v_perm byte-selects)
__device__ __forceinline__ s16x8 pack8(f32x4 x0, f32x4 x1) {
    union { s16x8 v; u32 w[4]; } r;
    r.w[0] = __builtin_amdgcn_perm(__float_as_uint(x0[1]), __float_as_uint(x0[0]), 0x07060302u);
    r.w[1] = __builtin_amdgcn_perm(__float_as_uint(x0[3]), __float_as_uint(x0[2]), 0x07060302u);
    r.w[2] = __builtin_amdgcn_perm(__float_as_uint(x1[1]), __float_as_uint(x1[0]), 0x07060302u);
    r.w[3] = __builtin_amdgcn_perm(__float_as_uint(x1[3]), __float_as_uint(x1[2]), 0x07060302u);
    return r.v;
}

#define BM 128
#define BN 128
#define BK 64

// C[r,n] = sum_k A[r,k]*B[n,k]; K-contiguous operands; fp32 operands converted
// to bf16 at LDS-write time (raw-f32 register prefetch hides HBM latency under
// the MFMA phase). LDS tiles XOR-swizzled: 16B chunk index ^= (row&7).
// EPI 1: s += tanh(acc + hidb[(r/196)*N+n] + bias1[n]+bias2[n]) * wscore[n];
//        16-lane reduce -> atomicAdd(scores[r])
// EPI 2: atomicAdd(outF[r*N+n], acc)   (split-K accumulate)
template<int EPI, bool AF32, bool BF32>
__global__ __launch_bounds__(256) void gemm_bt(
    const void* __restrict__ Ag, const void* __restrict__ B1, const void* __restrict__ B2,
    int lda, int ldb1, int ldb2, int ksplitB, int N, int klen,
    float* __restrict__ outF,
    const float* __restrict__ bias1, const float* __restrict__ bias2,
    const float* __restrict__ hidb, const float* __restrict__ wscore,
    float* __restrict__ scores)
{
    __shared__ __align__(16) u16 As[BM * BK];
    __shared__ __align__(16) u16 Bs[BN * BK];
    const int tid = threadIdx.x;
    const int l   = tid & 63;

    // XCD-aware bijective remap: 4 consecutive logical blocks (sharing an
    // A-panel) land on one XCD, temporally adjacent -> A fetched once into L2.
    const int nbx = gridDim.x;
    const int nwg = nbx * gridDim.y;
    const int p   = blockIdx.x + blockIdx.y * nbx;
    const int per = nwg >> 3;
    const int lg  = (p & 7) * per + (p >> 3);
    const int n0  = (lg % nbx) * BN;
    const int m0  = (lg / nbx) * BM;

    const int kbeg   = blockIdx.z * klen;
    const int nsteps = klen / BK;
    const int w  = tid >> 6;
    const int wr = (w >> 1) * 64;
    const int wc = (w & 1) * 64;
    const int srow = tid >> 3;        // staging row-in-group 0..31
    const int cs   = tid & 7;         // staging 16B-chunk 0..7

    f32x4 acc[4][4] = {};
    // raw prefetch registers (f32 path) / bf16 direct (bf16 path)
    f32x4 fa[8], fb[8];
    s16x8 ha[4], hb16[4];

    auto LOAD = [&](int kt) {
        #pragma unroll
        for (int c = 0; c < 4; ++c) {
            int row = c * 32 + srow;
            if constexpr (AF32) {
                const float* ap = (const float*)Ag + (size_t)(m0 + row) * lda + kt + cs * 8;
                fa[2*c]   = *(const f32x4*)ap;
                fa[2*c+1] = *(const f32x4*)(ap + 4);
            } else {
                ha[c] = *(const s16x8*)((const u16*)Ag + (size_t)(m0 + row) * lda + kt + cs * 8);
            }
            int kg = kt + cs * 8;
            if constexpr (BF32) {
                const float* bp = (kg < ksplitB)
                    ? ((const float*)B1 + (size_t)(n0 + row) * ldb1 + kg)
                    : ((const float*)B2 + (size_t)(n0 + row) * ldb2 + (kg - ksplitB));
                fb[2*c]   = *(const f32x4*)bp;
                fb[2*c+1] = *(const f32x4*)(bp + 4);
            } else {
                const u16* bp = (kg < ksplitB)
                    ? ((const u16*)B1 + (size_t)(n0 + row) * ldb1 + kg)
                    : ((const u16*)B2 + (size_t)(n0 + row) * ldb2 + (kg - ksplitB));
                hb16[c] = *(const s16x8*)bp;
            }
        }
    };

    LOAD(kbeg);

    for (int s = 0; s < nsteps; ++s) {
        __syncthreads();   // prior compute's LDS reads done
        #pragma unroll
        for (int c = 0; c < 4; ++c) {
            int row = c * 32 + srow;
            int sw = ((cs ^ (row & 7)) * 8);
            s16x8 va, vb;
            if constexpr (AF32) va = pack8(fa[2*c], fa[2*c+1]); else va = ha[c];
            if constexpr (BF32) vb = pack8(fb[2*c], fb[2*c+1]); else vb = hb16[c];
            *(s16x8*)(As + row * BK + sw) = va;
            *(s16x8*)(Bs + row * BK + sw) = vb;
        }
        __syncthreads();   // tile visible
        if (s + 1 < nsteps) LOAD(kbeg + (s + 1) * BK);   // issue next-tile loads
        #pragma unroll
        for (int kk = 0; kk < BK; kk += 32) {
            s16x8 af[4], bg[4];
            const int cb = (kk >> 3) + (l >> 4);   // unswizzled chunk 0..7
            #pragma unroll
            for (int i = 0; i < 4; ++i) {
                int ra = wr + i * 16 + (l & 15);
                af[i] = *(const s16x8*)(As + ra * BK + ((cb ^ (ra & 7)) * 8));
            }
            #pragma unroll
            for (int j = 0; j < 4; ++j) {
                int rb = wc + j * 16 + (l & 15);
                bg[j] = *(const s16x8*)(Bs + rb * BK + ((cb ^ (rb & 7)) * 8));
            }
            #pragma unroll
            for (int i = 0; i < 4; ++i)
                #pragma unroll
                for (int j = 0; j < 4; ++j)
                    acc[i][j] = __builtin_amdgcn_mfma_f32_16x16x32_bf16(af[i], bg[j], acc[i][j], 0, 0, 0);
        }
    }

    // C/D layout (m89-verified): col = lane&15, row = (lane>>4)*4 + reg
    const int col0 = l & 15;
    const int rgrp = l >> 4;

    if (EPI == 1) {
        float wsv[4], bs[4]; int gcol[4];
        #pragma unroll
        for (int j = 0; j < 4; ++j) {
            gcol[j] = n0 + wc + j * 16 + col0;
            wsv[j] = wscore[gcol[j]];
            bs[j]  = bias1[gcol[j]] + bias2[gcol[j]];
        }
        #pragma unroll
        for (int i = 0; i < 4; ++i) {
            #pragma unroll
            for (int q = 0; q < 4; ++q) {
                int grow = m0 + wr + i * 16 + rgrp * 4 + q;
                int bb = grow / 196;
                const float* hb = hidb + (size_t)bb * N;
                float s = 0.f;
                #pragma unroll
                for (int j = 0; j < 4; ++j) {
                    float x = acc[i][j][q] + hb[gcol[j]] + bs[j];
                    s += tanh_fast(x) * wsv[j];
                }
                s += __shfl_xor(s, 1);
                s += __shfl_xor(s, 2);
                s += __shfl_xor(s, 4);
                s += __shfl_xor(s, 8);
                if (col0 == 0) atomicAdd(&scores[grow], s);
            }
        }
    } else {
        #pragma unroll
        for (int j = 0; j < 4; ++j) {
            int gcol = n0 + wc + j * 16 + col0;
            #pragma unroll
            for (int i = 0; i < 4; ++i)
                #pragma unroll
                for (int q = 0; q < 4; ++q) {
                    int grow = m0 + wr + i * 16 + rgrp * 4 + q;
                    atomicAdd(&outF[(size_t)grow * N + gcol], acc[i][j][q]);
                }
        }
    }
}

// One block per batch row b: softmax over L=196 scores; att_res = sum_l p_l*att[b,l,:]
// (f32x4 loads, halves of the block cover even/odd l, LDS cross-half reduce);
// X[b] = [xt | att_res | h_prev] packed bf16 (K=1536) for the gates GEMM.
__global__ __launch_bounds__(256) void softmax_attres(
    const float* __restrict__ att, const float* __restrict__ scores,
    const float* __restrict__ xt, const float* __restrict__ h0,
    u16* __restrict__ X)
{
    const int b = blockIdx.x;
    const int tid = threadIdx.x;
    __shared__ float p[200];
    __shared__ float redm[4], reds[4];
    __shared__ float accu[128 * 4];

    float s = (tid < 196) ? scores[b * 196 + tid] : -3.0e38f;
    float m = s;
    #pragma unroll
    for (int d = 32; d; d >>= 1) m = fmaxf(m, __shfl_xor(m, d));
    if ((tid & 63) == 0) redm[tid >> 6] = m;
    __syncthreads();
    m = fmaxf(fmaxf(redm[0], redm[1]), fmaxf(redm[2], redm[3]));

    float e = (tid < 196) ? __expf(s - m) : 0.f;
    float sum = e;
    #pragma unroll
    for (int d = 32; d; d >>= 1) sum += __shfl_xor(sum, d);
    if ((tid & 63) == 0) reds[tid >> 6] = sum;
    __syncthreads();
    sum = reds[0] + reds[1] + reds[2] + reds[3];
    if (tid < 196) p[tid] = e / sum;
    __syncthreads();

    const float* attb = att + (size_t)b * 196 * 512;
    const int half = tid >> 7;           // waves 0,1 -> even l; waves 2,3 -> odd l
    const int e4   = (tid & 127) * 4;    // feature base 0..508
    f32x4 a = {0.f, 0.f, 0.f, 0.f};
    for (int lq = half; lq < 196; lq += 2) {
        f32x4 u = *(const f32x4*)(attb + (size_t)lq * 512 + e4);
        float pl = p[lq];
        a[0] = fmaf(pl, u[0], a[0]);
        a[1] = fmaf(pl, u[1], a[1]);
        a[2] = fmaf(pl, u[2], a[2]);
        a[3] = fmaf(pl, u[3], a[3]);
    }
    if (half) *(f32x4*)(accu + (tid & 127) * 4) = a;
    __syncthreads();

    u16* Xr = X + (size_t)b * 1536;
    if (!half) {
        f32x4 o = *(const f32x4*)(accu + tid * 4);
        a[0] += o[0]; a[1] += o[1]; a[2] += o[2]; a[3] += o[3];
        ((u32*)(Xr + 512))[tid * 2]     = ((u32)f2bf(a[1]) << 16) | (u32)f2bf(a[0]);
        ((u32*)(Xr + 512))[tid * 2 + 1] = ((u32)f2bf(a[3]) << 16) | (u32)f2bf(a[2]);
    }
    f32x2 xv = ((const f32x2*)(xt + (size_t)b * 512))[tid];
    ((u32*)Xr)[tid] = ((u32)f2bf(xv[1]) << 16) | (u32)f2bf(xv[0]);
    f32x2 hv = ((const f32x2*)(h0 + (size_t)b * 512))[tid];
    ((u32*)(Xr + 1024))[tid] = ((u32)f2bf(hv[1]) << 16) | (u32)f2bf(hv[0]);
}

// Elementwise LSTM: gate order i,f,g,o. out = [h | h | c] fp32.
__global__ __launch_bounds__(256) void lstm_ep(
    const float* __restrict__ gates, const float* __restrict__ c0, float* __restrict__ out)
{
    int idx = blockIdx.x * 256 + threadIdx.x;     // 0..262143
    int b = idx >> 9, hh = idx & 511;
    const float* g = gates + ((size_t)b << 11);
    float i_ = sigm(g[hh]);
    float f_ = sigm(g[512 + hh]);
    float g_ = tanh_fast(g[1024 + hh]);
    float o_ = sigm(g[1536 + hh]);
    float c = f_ * c0[idx] + i_ * g_;
    float h = o_ * tanh_fast(c);
    out[idx] = h;
    out[262144 + idx] = h;
    out[524288 + idx] = c;
}

extern "C" void kernel_launch(void* const* d_in, const int* in_sizes, int n_in,
                              void* d_out, int out_size, void* d_ws, size_t ws_size,
                              hipStream_t stream) {
    const float* xt   = (const float*)d_in[0];
    // d_in[1] = fc_feats (unused by reference)
    const float* att  = (const float*)d_in[2];
    const float* h0   = (const float*)d_in[3];
    const float* c0   = (const float*)d_in[4];
    const float* Wctx = (const float*)d_in[5];
    const float* bctx = (const float*)d_in[6];
    const float* Whid = (const float*)d_in[7];
    const float* bhid = (const float*)d_in[8];
    const float* wsc  = (const float*)d_in[9];
    // d_in[10] = b_score (cancels under softmax)
    const float* Wih  = (const float*)d_in[11];
    const float* Whh  = (const float*)d_in[12];
    float* out = (float*)d_out;

    char* ws = (char*)d_ws;
    float* hidb   = (float*)(ws);                 // 512*512 f32   = 1,048,576 B
    float* scores = (float*)(ws + 1048576);       // 100352 f32    =   401,408 B
    float* gates  = (float*)(ws + 1449984);       // 512*2048 f32  = 4,194,304 B
    u16*   X      = (u16*)  (ws + 5644288);       // 512*1536 bf16 = 1,572,864 B

    // zero all atomically-accumulated regions (hidb + scores + gates)
    hipMemsetAsync(ws, 0, 5644288, stream);

    // 1) hidb[b,a] += h_prev @ W_hid^T      (split-K=4; biases folded into EPI1)
    gemm_bt<2, true, true><<<dim3(4, 4, 4), 256, 0, stream>>>(
        h0, Whid, Whid, 512, 512, 512, 1 << 28, 512, 128,
        hidb, nullptr, nullptr, nullptr, nullptr, nullptr);

    // 2) scores[b,l] += sum_a tanh(att@Wctx^T + hidb + b_hid + b_ctx)*w_score
    gemm_bt<1, true, true><<<dim3(4, 784, 1), 256, 0, stream>>>(
        att, Wctx, Wctx, 512, 512, 512, 1 << 28, 512, 512,
        nullptr, bhid, bctx, hidb, wsc, scores);

    // 3) softmax + att_res + X = [xt | att_res | h_prev] (bf16)
    softmax_attres<<<512, 256, 0, stream>>>(att, scores, xt, h0, X);

    // 4) gates = X @ [W_ih | W_hh]^T   (M=512,N=2048,K=1536, split-K=4)
    gemm_bt<2, false, true><<<dim3(16, 4, 4), 256, 0, stream>>>(
        X, Wih, Whh, 1536, 1024, 512, 1024, 2048, 384,
        gates, nullptr, nullptr, nullptr, nullptr, nullptr);

    // 5) elementwise LSTM -> out = [h | h | c] fp32
    lstm_ep<<<1024, 256, 0, stream>>>(gates, c0, out);
}